// Round 6
// baseline (139.143 us; speedup 1.0000x reference)
//
#include <hip/hip_runtime.h>

// MultiScaleRetention on MI355X (gfx950)
// B=2, L=2048, D=1024, H=16, hd=64. fp32 in/out, bf16 MFMA internally.
//
// ws layout (ushort elems), 40 MB total:
//   q[4M] | k[4M] | vt[4M] | ret/xb[4M] (aliased: xb dead after qkv) |
//   wqb[1M] | wkb[1M] | wvb[1M] | wob[1M]
//   q,k,ret,xb: [B*L][1024] row-major bf16;  vt: [B][H*hd][L] bf16

typedef __attribute__((ext_vector_type(8))) short bf16x8;
typedef __attribute__((ext_vector_type(4))) float f32x4;
typedef __attribute__((ext_vector_type(16))) float f32x16;
typedef __attribute__((ext_vector_type(4))) unsigned short u16x4;
typedef __attribute__((ext_vector_type(8))) unsigned short u16x8;
typedef __attribute__((ext_vector_type(4))) unsigned int u32x4;

__device__ inline unsigned short f2bf(float f) {
    unsigned int u;
    __builtin_memcpy(&u, &f, 4);
    u += 0x7fffu + ((u >> 16) & 1u);
    return (unsigned short)(u >> 16);
}

__device__ inline f32x4 mfma16(bf16x8 a, bf16x8 b, f32x4 c) {
    return __builtin_amdgcn_mfma_f32_16x16x32_bf16(a, b, c, 0, 0, 0);
}
__device__ inline f32x16 mfma32(bf16x8 a, bf16x8 b, f32x16 c) {
    return __builtin_amdgcn_mfma_f32_32x32x16_bf16(a, b, c, 0, 0, 0);
}

__device__ inline void gl16(const unsigned short* g, unsigned short* l) {
    __builtin_amdgcn_global_load_lds(
        (const __attribute__((address_space(1))) unsigned int*)g,
        (__attribute__((address_space(3))) unsigned int*)l,
        16, 0, 0);
}

__device__ inline unsigned cvtpk(float lo, float hi) {
    unsigned r;
    asm("v_cvt_pk_bf16_f32 %0, %1, %2" : "=v"(r) : "v"(lo), "v"(hi));
    return r;
}

// ---------------------------------------------------------------------------
// Kernel 0: f32 -> bf16 conversion of x and the four weight matrices.
// ---------------------------------------------------------------------------
__global__ __launch_bounds__(256) void convert_bf16(
    const float* __restrict__ x,
    const float* __restrict__ wq, const float* __restrict__ wk,
    const float* __restrict__ wv, const float* __restrict__ wo,
    unsigned short* __restrict__ xb,
    unsigned short* __restrict__ wqb, unsigned short* __restrict__ wkb,
    unsigned short* __restrict__ wvb, unsigned short* __restrict__ wob)
{
    int cid = blockIdx.x * 256 + threadIdx.x;
    #pragma unroll
    for (int it = 0; it < 4; ++it, cid += 262144) {
        const float* src;
        unsigned short* dst;
        size_t off;
        if (cid < 524288) {
            src = x; dst = xb; off = (size_t)cid * 8;
        } else {
            const int t = cid - 524288;
            const int seg = t >> 17;
            off = (size_t)(t & 131071) * 8;
            src = seg == 0 ? wq : seg == 1 ? wk : seg == 2 ? wv : wo;
            dst = seg == 0 ? wqb : seg == 1 ? wkb : seg == 2 ? wvb : wob;
        }
        f32x4 a = *(const f32x4*)(src + off);
        f32x4 b = *(const f32x4*)(src + off + 4);
        u32x4 v = { cvtpk(a[0], a[1]), cvtpk(a[2], a[3]),
                    cvtpk(b[0], b[1]), cvtpk(b[2], b[3]) };
        *(u32x4*)(dst + off) = v;
    }
}

// ---------------------------------------------------------------------------
// Kernel 1: QKV projections, pure bf16, m97 structure + XOR bank swizzle.
// ---------------------------------------------------------------------------
__global__ __launch_bounds__(256) void qkv_bf16(
    const unsigned short* __restrict__ xb,
    const unsigned short* __restrict__ wqb, const unsigned short* __restrict__ wkb,
    const unsigned short* __restrict__ wvb,
    unsigned short* __restrict__ q, unsigned short* __restrict__ k,
    unsigned short* __restrict__ vt)
{
    __shared__ unsigned short sR[128 * 64];
    __shared__ unsigned short sL[128 * 64];

    const int z = blockIdx.z;
    const unsigned short* W = (z == 0) ? wqb : (z == 1) ? wkb : wvb;
    const unsigned short* Rs = (z < 2) ? xb : W;
    const unsigned short* Ls = (z < 2) ? W : xb;
    const int rblk = (z < 2) ? blockIdx.x : blockIdx.y;
    const int lblk = (z < 2) ? blockIdx.y : blockIdx.x;

    const int tid = threadIdx.x;
    const int l = tid & 63, w = tid >> 6;
    const int lrow = l & 15, koff4 = (l >> 4) * 4;
    const int swz = lrow & 7;            // per-lane read swizzle
    const int wrow = (w >> 1) * 64, wcol = (w & 1) * 64;

    f32x4 acc[4][4] = {};

    const int srow = w * 32 + (l >> 3);
    const int scol = ((l & 7) ^ ((l >> 3) & 7)) * 8;
    const unsigned short* gR = Rs + (size_t)(rblk * 128 + srow) * 1024 + scol;
    const unsigned short* gL = Ls + (size_t)(lblk * 128 + srow) * 1024 + scol;
    unsigned short* lRb = sR + (w * 32) * 64;
    unsigned short* lLb = sL + (w * 32) * 64;

    for (int kk = 0; kk < 1024; kk += 64) {
        #pragma unroll
        for (int p = 0; p < 4; ++p) {
            gl16(gR + (size_t)p * 8 * 1024 + kk, lRb + p * 512);
            gl16(gL + (size_t)p * 8 * 1024 + kk, lLb + p * 512);
        }
        __syncthreads();
        #pragma unroll
        for (int kt = 0; kt < 2; ++kt) {
            bf16x8 aL[4], bR[4];
            #pragma unroll
            for (int f = 0; f < 4; ++f) {
                const int co = ((kt * 4 + (l >> 4)) ^ swz) * 8;
                aL[f] = *(const bf16x8*)&sL[(wcol + f * 16 + lrow) * 64 + co];
                bR[f] = *(const bf16x8*)&sR[(wrow + f * 16 + lrow) * 64 + co];
            }
            #pragma unroll
            for (int af = 0; af < 4; ++af)
                #pragma unroll
                for (int bf = 0; bf < 4; ++bf)
                    acc[af][bf] = mfma16(aL[af], bR[bf], acc[af][bf]);
        }
        __syncthreads();
    }

    #pragma unroll
    for (int af = 0; af < 4; ++af) {
        #pragma unroll
        for (int bf = 0; bf < 4; ++bf) {
            const int m = rblk * 128 + wrow + bf * 16 + lrow;
            const int n0 = lblk * 128 + wcol + af * 16 + koff4;
            f32x4 v = acc[af][bf];
            unsigned p0 = cvtpk(v[0], v[1]), p1 = cvtpk(v[2], v[3]);
            u16x4 val = { (unsigned short)(p0 & 0xffff), (unsigned short)(p0 >> 16),
                          (unsigned short)(p1 & 0xffff), (unsigned short)(p1 >> 16) };
            if (z < 2) {
                unsigned short* dst = z ? k : q;
                *(u16x4*)(dst + (size_t)m * 1024 + n0) = val;
            } else {
                const int b = n0 >> 11;
                const int t = n0 & 2047;
                *(u16x4*)(vt + (size_t)(b * 1024 + m) * 2048 + t) = val;
            }
        }
    }
}

// ---------------------------------------------------------------------------
// Kernel 2: retention, barrier-free, XCD-localized. 1 wave = 32 q-rows.
// bid -> xcd = bid&7 owns heads bh in [4*xcd, 4*xcd+4): per-XCD K/V working
// set ~2MB < 4MB L2, so K/V re-reads are L2-hits. tw ordered heavy-first.
// ---------------------------------------------------------------------------
__global__ __launch_bounds__(64) void retention_direct(
    const unsigned short* __restrict__ q, const unsigned short* __restrict__ k,
    const unsigned short* __restrict__ vt, const float* __restrict__ gammas,
    unsigned short* __restrict__ ret)
{
    const int bid = blockIdx.x;
    const int xcd = bid & 7;
    const int idx = bid >> 3;               // 0..255
    const int bh  = (xcd << 2) | (idx & 3); // 4 heads per XCD
    const int tw  = 63 - (idx >> 2);        // heavy blocks first
    const int b = bh >> 4, h = bh & 15;
    const float lg = log2f(gammas[h]);      // < 0
    const int cut_i = (int)(45.0f / (-lg));

    const int l = threadIdx.x;
    const int l31 = l & 31, hi = l >> 5;
    const int tw0 = tw << 5;
    const int tq = tw0 + l31;

    // Q fragments (B operand: n=l31 -> t, k = hi*8+j, +16 per kt)
    const unsigned short* qp = q + (size_t)(b * 2048 + tq) * 1024 + h * 64 + (hi << 3);
    bf16x8 qf[4];
    #pragma unroll
    for (int kt = 0; kt < 4; ++kt) qf[kt] = *(const bf16x8*)(qp + kt * 16);

    // cf[r] = gamma^(31 - crow(r)), crow = (r&3)+4*hi+8*(r>>2)
    float cf[16];
    #pragma unroll
    for (int r = 0; r < 16; ++r) {
        const int crow = (r & 3) + (hi << 2) + ((r >> 2) << 3);
        cf[r] = exp2f((float)(31 - crow) * lg);
    }

    const size_t kbase = (size_t)(b * 2048 + l31) * 1024 + h * 64 + (hi << 3);
    const size_t vb0 = (size_t)(b * 1024 + h * 64 + l31) * 2048 + (hi << 3);
    const size_t vb1 = vb0 + (size_t)32 * 2048;

    auto ldk = [&](int sb, bf16x8* kf) {
        const unsigned short* p = k + kbase + (size_t)(sb << 5) * 1024;
        #pragma unroll
        for (int kt = 0; kt < 4; ++kt) kf[kt] = *(const bf16x8*)(p + kt * 16);
    };
    auto ldv = [&](int sb, bf16x8* vf) {
        const unsigned short* p0 = vt + vb0 + (sb << 5);
        const unsigned short* p1 = vt + vb1 + (sb << 5);
        vf[0] = *(const bf16x8*)(p0);
        vf[1] = *(const bf16x8*)(p0 + 16);
        vf[2] = *(const bf16x8*)(p1);
        vf[3] = *(const bf16x8*)(p1 + 16);
    };

    int sb_lo = tw0 - 31 - cut_i;
    sb_lo = (sb_lo <= 0) ? 0 : (sb_lo >> 5);

    bf16x8 kc[4], vc[4], kn[4], vn[4];
    ldk(sb_lo, kc);
    ldv(sb_lo, vc);

    f32x16 acc0 = {}, acc1 = {};

    for (int sb = sb_lo; sb <= tw; ++sb) {
        if (sb < tw) { ldk(sb + 1, kn); ldv(sb + 1, vn); }
        const int s0 = sb << 5;
        // QK^T swapped: A=K (m=s), B=Q (n=t). D: col=t=l31, row=s=crow(r).
        f32x16 sc = {};
        #pragma unroll
        for (int kt = 0; kt < 4; ++kt) sc = mfma32(kc[kt], qf[kt], sc);

        const float rowf = 0.125f * exp2f((float)(tq - s0 - 31) * lg);
        const bool diag = (sb == tw);
        const int dtq = tq - s0;
        float wv_[16];
        #pragma unroll
        for (int r = 0; r < 16; ++r) {
            float t_ = sc[r] * rowf * cf[r];
            if (diag) {
                const int crow = (r & 3) + (hi << 2) + ((r >> 2) << 3);
                t_ = (dtq >= crow) ? t_ : 0.0f;
            }
            wv_[r] = t_;
        }
        unsigned pk_[8];
        #pragma unroll
        for (int i = 0; i < 8; ++i) pk_[i] = cvtpk(wv_[2 * i], wv_[2 * i + 1]);
        asm("v_permlane32_swap_b32 %0, %1" : "+v"(pk_[0]), "+v"(pk_[2]));
        asm("v_permlane32_swap_b32 %0, %1" : "+v"(pk_[1]), "+v"(pk_[3]));
        asm("v_permlane32_swap_b32 %0, %1" : "+v"(pk_[4]), "+v"(pk_[6]));
        asm("v_permlane32_swap_b32 %0, %1" : "+v"(pk_[5]), "+v"(pk_[7]));
        u32x4 f0v = { pk_[0], pk_[1], pk_[2], pk_[3] };
        u32x4 f1v = { pk_[4], pk_[5], pk_[6], pk_[7] };
        const bf16x8 pa0 = __builtin_bit_cast(bf16x8, f0v);
        const bf16x8 pa1 = __builtin_bit_cast(bf16x8, f1v);
        acc0 = mfma32(pa0, vc[0], acc0);
        acc0 = mfma32(pa1, vc[1], acc0);
        acc1 = mfma32(pa0, vc[2], acc1);
        acc1 = mfma32(pa1, vc[3], acc1);

        if (sb < tw) {
            #pragma unroll
            for (int i = 0; i < 4; ++i) { kc[i] = kn[i]; vc[i] = vn[i]; }
        }
    }

    #pragma unroll
    for (int r = 0; r < 16; ++r) {
        const int tl = (r & 3) + (hi << 2) + ((r >> 2) << 3);
        unsigned short* dst = ret + (size_t)(b * 2048 + tw0 + tl) * 1024 + h * 64 + l31;
        dst[0]  = f2bf(acc0[r]);
        dst[32] = f2bf(acc1[r]);
    }
}

// ---------------------------------------------------------------------------
// Kernel 3: out = ret @ wo.T, bf16 in / f32 out, same swizzled m97 structure.
// ---------------------------------------------------------------------------
__global__ __launch_bounds__(256) void out_bf16(
    const unsigned short* __restrict__ ret, const unsigned short* __restrict__ wob,
    float* __restrict__ out)
{
    __shared__ unsigned short sR[128 * 64];
    __shared__ unsigned short sL[128 * 64];

    const int rblk = blockIdx.x;
    const int lblk = blockIdx.y;

    const int tid = threadIdx.x;
    const int l = tid & 63, w = tid >> 6;
    const int lrow = l & 15, koff4 = (l >> 4) * 4;
    const int swz = lrow & 7;
    const int wrow = (w >> 1) * 64, wcol = (w & 1) * 64;

    f32x4 acc[4][4] = {};

    const int srow = w * 32 + (l >> 3);
    const int scol = ((l & 7) ^ ((l >> 3) & 7)) * 8;
    const unsigned short* gR = ret + (size_t)(rblk * 128 + srow) * 1024 + scol;
    const unsigned short* gL = wob + (size_t)(lblk * 128 + srow) * 1024 + scol;
    unsigned short* lRb = sR + (w * 32) * 64;
    unsigned short* lLb = sL + (w * 32) * 64;

    for (int kk = 0; kk < 1024; kk += 64) {
        #pragma unroll
        for (int p = 0; p < 4; ++p) {
            gl16(gR + (size_t)p * 8 * 1024 + kk, lRb + p * 512);
            gl16(gL + (size_t)p * 8 * 1024 + kk, lLb + p * 512);
        }
        __syncthreads();
        #pragma unroll
        for (int kt = 0; kt < 2; ++kt) {
            bf16x8 aL[4], bR[4];
            #pragma unroll
            for (int f = 0; f < 4; ++f) {
                const int co = ((kt * 4 + (l >> 4)) ^ swz) * 8;
                aL[f] = *(const bf16x8*)&sL[(wcol + f * 16 + lrow) * 64 + co];
                bR[f] = *(const bf16x8*)&sR[(wrow + f * 16 + lrow) * 64 + co];
            }
            #pragma unroll
            for (int af = 0; af < 4; ++af)
                #pragma unroll
                for (int bf = 0; bf < 4; ++bf)
                    acc[af][bf] = mfma16(aL[af], bR[bf], acc[af][bf]);
        }
        __syncthreads();
    }

    #pragma unroll
    for (int af = 0; af < 4; ++af)
        #pragma unroll
        for (int bf = 0; bf < 4; ++bf) {
            const int m = rblk * 128 + wrow + bf * 16 + lrow;
            const int n0 = lblk * 128 + wcol + af * 16 + koff4;
            *(f32x4*)(out + (size_t)m * 1024 + n0) = acc[af][bf];
        }
}

extern "C" void kernel_launch(void* const* d_in, const int* in_sizes, int n_in,
                              void* d_out, int out_size, void* d_ws, size_t ws_size,
                              hipStream_t stream) {
    const float* x      = (const float*)d_in[0];
    const float* wq     = (const float*)d_in[1];
    const float* wk     = (const float*)d_in[2];
    const float* wv     = (const float*)d_in[3];
    const float* wo     = (const float*)d_in[4];
    const float* gammas = (const float*)d_in[5];
    float* out = (float*)d_out;

    unsigned short* ws = (unsigned short*)d_ws;
    unsigned short* q   = ws;
    unsigned short* k   = ws + (size_t)4 * 1024 * 1024;
    unsigned short* vt  = ws + (size_t)8 * 1024 * 1024;
    unsigned short* ret = ws + (size_t)12 * 1024 * 1024;   // also xb (dead after qkv)
    unsigned short* xb  = ret;
    unsigned short* wqb = ws + (size_t)16 * 1024 * 1024;
    unsigned short* wkb = ws + (size_t)17 * 1024 * 1024;
    unsigned short* wvb = ws + (size_t)18 * 1024 * 1024;
    unsigned short* wob = ws + (size_t)19 * 1024 * 1024;

    convert_bf16<<<1024, 256, 0, stream>>>(x, wq, wk, wv, wo, xb, wqb, wkb, wvb, wob);
    qkv_bf16<<<dim3(32, 8, 3), 256, 0, stream>>>(xb, wqb, wkb, wvb, q, k, vt);
    retention_direct<<<2048, 64, 0, stream>>>(q, k, vt, gammas, ret);
    out_bf16<<<dim3(32, 8), 256, 0, stream>>>(ret, wob, out);
}

// Round 7
// 112.565 us; speedup vs baseline: 1.2361x; 1.2361x over previous
//
#include <hip/hip_runtime.h>

// MultiScaleRetention on MI355X (gfx950)
// B=2, L=2048, D=1024, H=16, hd=64. fp32 in/out, bf16 MFMA internally.
//
// ws layout (ushort elems), 40 MB total:
//   qf[4M] | kf[4M] | vf[4M] | ret/xb[4M] (aliased) | wqb|wkb|wvb|wob [1M each]
//   qf,kf: fragment-linear [(b*16+h)*64+sb][kt:4][lane:64][8]
//          elem (b, s, h*64+dd) at ((b*16+h)*64+(s>>5))*2048 + (dd>>4)*512
//          + ((dd>>3)&1)*256 + (s&31)*8 + (dd&7)
//   vf:    fragment-linear [(b*16+h)*64+sb][i:4][lane:64][8]
//          elem V[b][t][h*64+dd] at ((b*16+h)*64+(t>>5))*2048
//          + ((dd>>5)*2+((t>>4)&1))*512 + ((t>>3)&1)*256 + (dd&31)*8 + (t&7)
//   ret,xb: [B*L][1024] row-major bf16

typedef __attribute__((ext_vector_type(8))) short bf16x8;
typedef __attribute__((ext_vector_type(4))) float f32x4;
typedef __attribute__((ext_vector_type(16))) float f32x16;
typedef __attribute__((ext_vector_type(4))) unsigned short u16x4;
typedef __attribute__((ext_vector_type(8))) unsigned short u16x8;
typedef __attribute__((ext_vector_type(4))) unsigned int u32x4;

__device__ inline unsigned short f2bf(float f) {
    unsigned int u;
    __builtin_memcpy(&u, &f, 4);
    u += 0x7fffu + ((u >> 16) & 1u);
    return (unsigned short)(u >> 16);
}

__device__ inline f32x4 mfma16(bf16x8 a, bf16x8 b, f32x4 c) {
    return __builtin_amdgcn_mfma_f32_16x16x32_bf16(a, b, c, 0, 0, 0);
}
__device__ inline f32x16 mfma32(bf16x8 a, bf16x8 b, f32x16 c) {
    return __builtin_amdgcn_mfma_f32_32x32x16_bf16(a, b, c, 0, 0, 0);
}

__device__ inline void gl16(const unsigned short* g, unsigned short* l) {
    __builtin_amdgcn_global_load_lds(
        (const __attribute__((address_space(1))) unsigned int*)g,
        (__attribute__((address_space(3))) unsigned int*)l,
        16, 0, 0);
}

__device__ inline unsigned cvtpk(float lo, float hi) {
    unsigned r;
    asm("v_cvt_pk_bf16_f32 %0, %1, %2" : "=v"(r) : "v"(lo), "v"(hi));
    return r;
}

// ---------------------------------------------------------------------------
// Kernel 0: f32 -> bf16 conversion of x and the four weight matrices.
// ---------------------------------------------------------------------------
__global__ __launch_bounds__(256) void convert_bf16(
    const float* __restrict__ x,
    const float* __restrict__ wq, const float* __restrict__ wk,
    const float* __restrict__ wv, const float* __restrict__ wo,
    unsigned short* __restrict__ xb,
    unsigned short* __restrict__ wqb, unsigned short* __restrict__ wkb,
    unsigned short* __restrict__ wvb, unsigned short* __restrict__ wob)
{
    int cid = blockIdx.x * 256 + threadIdx.x;
    #pragma unroll
    for (int it = 0; it < 4; ++it, cid += 262144) {
        const float* src;
        unsigned short* dst;
        size_t off;
        if (cid < 524288) {
            src = x; dst = xb; off = (size_t)cid * 8;
        } else {
            const int t = cid - 524288;
            const int seg = t >> 17;
            off = (size_t)(t & 131071) * 8;
            src = seg == 0 ? wq : seg == 1 ? wk : seg == 2 ? wv : wo;
            dst = seg == 0 ? wqb : seg == 1 ? wkb : seg == 2 ? wvb : wob;
        }
        f32x4 a = *(const f32x4*)(src + off);
        f32x4 b = *(const f32x4*)(src + off + 4);
        u32x4 v = { cvtpk(a[0], a[1]), cvtpk(a[2], a[3]),
                    cvtpk(b[0], b[1]), cvtpk(b[2], b[3]) };
        *(u32x4*)(dst + off) = v;
    }
}

// ---------------------------------------------------------------------------
// Kernel 1: QKV projections, pure bf16, m97 structure + XOR bank swizzle.
// Epilogue writes MFMA-fragment-linear layouts (see header comment) so the
// retention kernel's tile loads are fully coalesced (1KB/wave-instruction).
// ---------------------------------------------------------------------------
__global__ __launch_bounds__(256) void qkv_bf16(
    const unsigned short* __restrict__ xb,
    const unsigned short* __restrict__ wqb, const unsigned short* __restrict__ wkb,
    const unsigned short* __restrict__ wvb,
    unsigned short* __restrict__ qfr, unsigned short* __restrict__ kfr,
    unsigned short* __restrict__ vfr)
{
    __shared__ unsigned short sR[128 * 64];
    __shared__ unsigned short sL[128 * 64];

    const int z = blockIdx.z;
    const unsigned short* W = (z == 0) ? wqb : (z == 1) ? wkb : wvb;
    const unsigned short* Rs = (z < 2) ? xb : W;
    const unsigned short* Ls = (z < 2) ? W : xb;
    const int rblk = (z < 2) ? blockIdx.x : blockIdx.y;
    const int lblk = (z < 2) ? blockIdx.y : blockIdx.x;

    const int tid = threadIdx.x;
    const int l = tid & 63, w = tid >> 6;
    const int lrow = l & 15, koff4 = (l >> 4) * 4;
    const int swz = lrow & 7;            // per-lane read swizzle
    const int wrow = (w >> 1) * 64, wcol = (w & 1) * 64;

    f32x4 acc[4][4] = {};

    const int srow = w * 32 + (l >> 3);
    const int scol = ((l & 7) ^ ((l >> 3) & 7)) * 8;
    const unsigned short* gR = Rs + (size_t)(rblk * 128 + srow) * 1024 + scol;
    const unsigned short* gL = Ls + (size_t)(lblk * 128 + srow) * 1024 + scol;
    unsigned short* lRb = sR + (w * 32) * 64;
    unsigned short* lLb = sL + (w * 32) * 64;

    for (int kk = 0; kk < 1024; kk += 64) {
        #pragma unroll
        for (int p = 0; p < 4; ++p) {
            gl16(gR + (size_t)p * 8 * 1024 + kk, lRb + p * 512);
            gl16(gL + (size_t)p * 8 * 1024 + kk, lLb + p * 512);
        }
        __syncthreads();
        #pragma unroll
        for (int kt = 0; kt < 2; ++kt) {
            bf16x8 aL[4], bR[4];
            #pragma unroll
            for (int f = 0; f < 4; ++f) {
                const int co = ((kt * 4 + (l >> 4)) ^ swz) * 8;
                aL[f] = *(const bf16x8*)&sL[(wcol + f * 16 + lrow) * 64 + co];
                bR[f] = *(const bf16x8*)&sR[(wrow + f * 16 + lrow) * 64 + co];
            }
            #pragma unroll
            for (int af = 0; af < 4; ++af)
                #pragma unroll
                for (int bf = 0; bf < 4; ++bf)
                    acc[af][bf] = mfma16(aL[af], bR[bf], acc[af][bf]);
        }
        __syncthreads();
    }

    // D col (= right local) = lane&15, row (= left local) = (lane>>4)*4 + r
    #pragma unroll
    for (int af = 0; af < 4; ++af) {
        #pragma unroll
        for (int bf = 0; bf < 4; ++bf) {
            const int m = rblk * 128 + wrow + bf * 16 + lrow;     // right index
            const int n0 = lblk * 128 + wcol + af * 16 + koff4;   // left index (4 consec)
            f32x4 v = acc[af][bf];
            unsigned p0 = cvtpk(v[0], v[1]), p1 = cvtpk(v[2], v[3]);
            u16x4 val = { (unsigned short)(p0 & 0xffff), (unsigned short)(p0 >> 16),
                          (unsigned short)(p1 & 0xffff), (unsigned short)(p1 >> 16) };
            if (z < 2) {
                // m = token global, n0 = feature (4 consec within one oct)
                const int bq = m >> 11, s = m & 2047;
                const int h2 = n0 >> 6, dd = n0 & 63;
                const size_t addr = (size_t)((bq * 16 + h2) * 64 + (s >> 5)) * 2048
                                  + (size_t)(dd >> 4) * 512 + (size_t)((dd >> 3) & 1) * 256
                                  + (size_t)(s & 31) * 8 + (dd & 7);
                unsigned short* dst = z ? kfr : qfr;
                *(u16x4*)(dst + addr) = val;
            } else {
                // m = feature, n0 = token (4 consec within one oct)
                const int h2 = m >> 6, dd = m & 63;
                const int bq = n0 >> 11, t = n0 & 2047;
                const size_t addr = (size_t)((bq * 16 + h2) * 64 + (t >> 5)) * 2048
                                  + (size_t)((dd >> 5) * 2 + ((t >> 4) & 1)) * 512
                                  + (size_t)((t >> 3) & 1) * 256
                                  + (size_t)(dd & 31) * 8 + (t & 7);
                *(u16x4*)(vfr + addr) = val;
            }
        }
    }
}

// ---------------------------------------------------------------------------
// Kernel 2: retention, barrier-free, XCD-localized, fragment-linear K/V/Q:
// every tile load is base + sb*2048 + slot*512 + lane*8 -> 1KB coalesced.
// ---------------------------------------------------------------------------
__global__ __launch_bounds__(64) void retention_direct(
    const unsigned short* __restrict__ qfr, const unsigned short* __restrict__ kfr,
    const unsigned short* __restrict__ vfr, const float* __restrict__ gammas,
    unsigned short* __restrict__ ret)
{
    const int bid = blockIdx.x;
    const int xcd = bid & 7;
    const int idx = bid >> 3;               // 0..255
    const int bh  = (xcd << 2) | (idx & 3); // 4 heads per XCD -> ~2MB L2 set
    const int tw  = 63 - (idx >> 2);        // heavy blocks first
    const int b = bh >> 4, h = bh & 15;
    const float lg = log2f(gammas[h]);      // < 0
    const int cut_i = (int)(45.0f / (-lg));

    const int l = threadIdx.x;
    const int l31 = l & 31, hi = l >> 5;
    const int tw0 = tw << 5;
    const int tq = tw0 + l31;

    const size_t hbase = (size_t)((b * 16 + h) * 64) * 2048;
    const unsigned short* qfb = qfr + hbase + l * 8;
    const unsigned short* kfb = kfr + hbase + l * 8;
    const unsigned short* vfb = vfr + hbase + l * 8;

    // Q fragments (B operand: n=l31 -> t, k = hi*8+j, +16 per kt)
    bf16x8 qf[4];
    #pragma unroll
    for (int kt = 0; kt < 4; ++kt)
        qf[kt] = *(const bf16x8*)(qfb + (size_t)tw * 2048 + kt * 512);

    // cf[r] = gamma^(31 - crow(r)), crow = (r&3)+4*hi+8*(r>>2)
    float cf[16];
    #pragma unroll
    for (int r = 0; r < 16; ++r) {
        const int crow = (r & 3) + (hi << 2) + ((r >> 2) << 3);
        cf[r] = exp2f((float)(31 - crow) * lg);
    }

    auto ldk = [&](int sb, bf16x8* kf) {
        const unsigned short* p = kfb + (size_t)sb * 2048;
        #pragma unroll
        for (int kt = 0; kt < 4; ++kt) kf[kt] = *(const bf16x8*)(p + kt * 512);
    };
    auto ldv = [&](int sb, bf16x8* vf) {
        const unsigned short* p = vfb + (size_t)sb * 2048;
        #pragma unroll
        for (int i = 0; i < 4; ++i) vf[i] = *(const bf16x8*)(p + i * 512);
    };

    int sb_lo = tw0 - 31 - cut_i;
    sb_lo = (sb_lo <= 0) ? 0 : (sb_lo >> 5);

    bf16x8 kc[4], vc[4], kn[4], vn[4];
    ldk(sb_lo, kc);
    ldv(sb_lo, vc);

    f32x16 acc0 = {}, acc1 = {};

    for (int sb = sb_lo; sb <= tw; ++sb) {
        if (sb < tw) { ldk(sb + 1, kn); ldv(sb + 1, vn); }
        const int s0 = sb << 5;
        // QK^T swapped: A=K (m=s), B=Q (n=t). D: col=t=l31, row=s=crow(r).
        f32x16 sc = {};
        #pragma unroll
        for (int kt = 0; kt < 4; ++kt) sc = mfma32(kc[kt], qf[kt], sc);

        const float rowf = 0.125f * exp2f((float)(tq - s0 - 31) * lg);
        const bool diag = (sb == tw);
        const int dtq = tq - s0;
        float wv_[16];
        #pragma unroll
        for (int r = 0; r < 16; ++r) {
            float t_ = sc[r] * rowf * cf[r];
            if (diag) {
                const int crow = (r & 3) + (hi << 2) + ((r >> 2) << 3);
                t_ = (dtq >= crow) ? t_ : 0.0f;
            }
            wv_[r] = t_;
        }
        unsigned pk_[8];
        #pragma unroll
        for (int i = 0; i < 8; ++i) pk_[i] = cvtpk(wv_[2 * i], wv_[2 * i + 1]);
        asm("v_permlane32_swap_b32 %0, %1" : "+v"(pk_[0]), "+v"(pk_[2]));
        asm("v_permlane32_swap_b32 %0, %1" : "+v"(pk_[1]), "+v"(pk_[3]));
        asm("v_permlane32_swap_b32 %0, %1" : "+v"(pk_[4]), "+v"(pk_[6]));
        asm("v_permlane32_swap_b32 %0, %1" : "+v"(pk_[5]), "+v"(pk_[7]));
        u32x4 f0v = { pk_[0], pk_[1], pk_[2], pk_[3] };
        u32x4 f1v = { pk_[4], pk_[5], pk_[6], pk_[7] };
        const bf16x8 pa0 = __builtin_bit_cast(bf16x8, f0v);
        const bf16x8 pa1 = __builtin_bit_cast(bf16x8, f1v);
        // PV: A=P (m=t), B=V (n=d, k=s)
        acc0 = mfma32(pa0, vc[0], acc0);
        acc0 = mfma32(pa1, vc[1], acc0);
        acc1 = mfma32(pa0, vc[2], acc1);
        acc1 = mfma32(pa1, vc[3], acc1);

        if (sb < tw) {
            #pragma unroll
            for (int i = 0; i < 4; ++i) { kc[i] = kn[i]; vc[i] = vn[i]; }
        }
    }

    // store: acc col=d=l31(+32), row t-local = crow(r); ret row-major
    #pragma unroll
    for (int r = 0; r < 16; ++r) {
        const int tl = (r & 3) + (hi << 2) + ((r >> 2) << 3);
        unsigned short* dst = ret + (size_t)(b * 2048 + tw0 + tl) * 1024 + h * 64 + l31;
        dst[0]  = f2bf(acc0[r]);
        dst[32] = f2bf(acc1[r]);
    }
}

// ---------------------------------------------------------------------------
// Kernel 3: out = ret @ wo.T, bf16 in / f32 out, same swizzled m97 structure.
// ---------------------------------------------------------------------------
__global__ __launch_bounds__(256) void out_bf16(
    const unsigned short* __restrict__ ret, const unsigned short* __restrict__ wob,
    float* __restrict__ out)
{
    __shared__ unsigned short sR[128 * 64];
    __shared__ unsigned short sL[128 * 64];

    const int rblk = blockIdx.x;
    const int lblk = blockIdx.y;

    const int tid = threadIdx.x;
    const int l = tid & 63, w = tid >> 6;
    const int lrow = l & 15, koff4 = (l >> 4) * 4;
    const int swz = lrow & 7;
    const int wrow = (w >> 1) * 64, wcol = (w & 1) * 64;

    f32x4 acc[4][4] = {};

    const int srow = w * 32 + (l >> 3);
    const int scol = ((l & 7) ^ ((l >> 3) & 7)) * 8;
    const unsigned short* gR = ret + (size_t)(rblk * 128 + srow) * 1024 + scol;
    const unsigned short* gL = wob + (size_t)(lblk * 128 + srow) * 1024 + scol;
    unsigned short* lRb = sR + (w * 32) * 64;
    unsigned short* lLb = sL + (w * 32) * 64;

    for (int kk = 0; kk < 1024; kk += 64) {
        #pragma unroll
        for (int p = 0; p < 4; ++p) {
            gl16(gR + (size_t)p * 8 * 1024 + kk, lRb + p * 512);
            gl16(gL + (size_t)p * 8 * 1024 + kk, lLb + p * 512);
        }
        __syncthreads();
        #pragma unroll
        for (int kt = 0; kt < 2; ++kt) {
            bf16x8 aL[4], bR[4];
            #pragma unroll
            for (int f = 0; f < 4; ++f) {
                const int co = ((kt * 4 + (l >> 4)) ^ swz) * 8;
                aL[f] = *(const bf16x8*)&sL[(wcol + f * 16 + lrow) * 64 + co];
                bR[f] = *(const bf16x8*)&sR[(wrow + f * 16 + lrow) * 64 + co];
            }
            #pragma unroll
            for (int af = 0; af < 4; ++af)
                #pragma unroll
                for (int bf = 0; bf < 4; ++bf)
                    acc[af][bf] = mfma16(aL[af], bR[bf], acc[af][bf]);
        }
        __syncthreads();
    }

    #pragma unroll
    for (int af = 0; af < 4; ++af)
        #pragma unroll
        for (int bf = 0; bf < 4; ++bf) {
            const int m = rblk * 128 + wrow + bf * 16 + lrow;
            const int n0 = lblk * 128 + wcol + af * 16 + koff4;
            *(f32x4*)(out + (size_t)m * 1024 + n0) = acc[af][bf];
        }
}

extern "C" void kernel_launch(void* const* d_in, const int* in_sizes, int n_in,
                              void* d_out, int out_size, void* d_ws, size_t ws_size,
                              hipStream_t stream) {
    const float* x      = (const float*)d_in[0];
    const float* wq     = (const float*)d_in[1];
    const float* wk     = (const float*)d_in[2];
    const float* wv     = (const float*)d_in[3];
    const float* wo     = (const float*)d_in[4];
    const float* gammas = (const float*)d_in[5];
    float* out = (float*)d_out;

    unsigned short* ws = (unsigned short*)d_ws;
    unsigned short* qf  = ws;
    unsigned short* kf  = ws + (size_t)4 * 1024 * 1024;
    unsigned short* vf  = ws + (size_t)8 * 1024 * 1024;
    unsigned short* ret = ws + (size_t)12 * 1024 * 1024;   // also xb (dead after qkv)
    unsigned short* xb  = ret;
    unsigned short* wqb = ws + (size_t)16 * 1024 * 1024;
    unsigned short* wkb = ws + (size_t)17 * 1024 * 1024;
    unsigned short* wvb = ws + (size_t)18 * 1024 * 1024;
    unsigned short* wob = ws + (size_t)19 * 1024 * 1024;

    convert_bf16<<<1024, 256, 0, stream>>>(x, wq, wk, wv, wo, xb, wqb, wkb, wvb, wob);
    qkv_bf16<<<dim3(32, 8, 3), 256, 0, stream>>>(xb, wqb, wkb, wvb, qf, kf, vf);
    retention_direct<<<2048, 64, 0, stream>>>(qf, kf, vf, gammas, ret);
    out_bf16<<<dim3(32, 8), 256, 0, stream>>>(ret, wob, out);
}

// Round 8
// 96.476 us; speedup vs baseline: 1.4423x; 1.1668x over previous
//
#include <hip/hip_runtime.h>

// MultiScaleRetention on MI355X (gfx950)
// B=2, L=2048, D=1024, H=16, hd=64. fp32 in/out, bf16 MFMA internally.
//
// ws layout (ushort elems), 40 MB total:
//   qf[4M] | kf[4M] | vf[4M] | ret/xb[4M] (aliased) | wqb|wkb|wvb|wob [1M each]
//   qf,kf: fragment-linear [(b*16+h)*64+sb][kt:4][lane:64][8]
//          elem (b, s, h*64+dd) at ((b*16+h)*64+(s>>5))*2048 + (dd>>4)*512
//          + ((dd>>3)&1)*256 + (s&31)*8 + (dd&7)
//   vf:    fragment-linear [(b*16+h)*64+sb][i:4][lane:64][8]
//          elem V[b][t][h*64+dd] at ((b*16+h)*64+(t>>5))*2048
//          + ((dd>>5)*2+((t>>4)&1))*512 + ((t>>3)&1)*256 + (dd&31)*8 + (t&7)
//   ret,xb: [B*L][1024] row-major bf16

typedef __attribute__((ext_vector_type(8))) short bf16x8;
typedef __attribute__((ext_vector_type(4))) float f32x4;
typedef __attribute__((ext_vector_type(16))) float f32x16;
typedef __attribute__((ext_vector_type(4))) unsigned short u16x4;
typedef __attribute__((ext_vector_type(8))) unsigned short u16x8;
typedef __attribute__((ext_vector_type(4))) unsigned int u32x4;

__device__ inline unsigned short f2bf(float f) {
    unsigned int u;
    __builtin_memcpy(&u, &f, 4);
    u += 0x7fffu + ((u >> 16) & 1u);
    return (unsigned short)(u >> 16);
}

__device__ inline f32x4 mfma16(bf16x8 a, bf16x8 b, f32x4 c) {
    return __builtin_amdgcn_mfma_f32_16x16x32_bf16(a, b, c, 0, 0, 0);
}
__device__ inline f32x16 mfma32(bf16x8 a, bf16x8 b, f32x16 c) {
    return __builtin_amdgcn_mfma_f32_32x32x16_bf16(a, b, c, 0, 0, 0);
}

__device__ inline void gl16(const unsigned short* g, unsigned short* l) {
    __builtin_amdgcn_global_load_lds(
        (const __attribute__((address_space(1))) unsigned int*)g,
        (__attribute__((address_space(3))) unsigned int*)l,
        16, 0, 0);
}

__device__ inline unsigned cvtpk(float lo, float hi) {
    unsigned r;
    asm("v_cvt_pk_bf16_f32 %0, %1, %2" : "=v"(r) : "v"(lo), "v"(hi));
    return r;
}

// ---------------------------------------------------------------------------
// Kernel 0: f32 -> bf16 conversion of x and the four weight matrices.
// ---------------------------------------------------------------------------
__global__ __launch_bounds__(256) void convert_bf16(
    const float* __restrict__ x,
    const float* __restrict__ wq, const float* __restrict__ wk,
    const float* __restrict__ wv, const float* __restrict__ wo,
    unsigned short* __restrict__ xb,
    unsigned short* __restrict__ wqb, unsigned short* __restrict__ wkb,
    unsigned short* __restrict__ wvb, unsigned short* __restrict__ wob)
{
    int cid = blockIdx.x * 256 + threadIdx.x;
    #pragma unroll
    for (int it = 0; it < 4; ++it, cid += 262144) {
        const float* src;
        unsigned short* dst;
        size_t off;
        if (cid < 524288) {
            src = x; dst = xb; off = (size_t)cid * 8;
        } else {
            const int t = cid - 524288;
            const int seg = t >> 17;
            off = (size_t)(t & 131071) * 8;
            src = seg == 0 ? wq : seg == 1 ? wk : seg == 2 ? wv : wo;
            dst = seg == 0 ? wqb : seg == 1 ? wkb : seg == 2 ? wvb : wob;
        }
        f32x4 a = *(const f32x4*)(src + off);
        f32x4 b = *(const f32x4*)(src + off + 4);
        u32x4 v = { cvtpk(a[0], a[1]), cvtpk(a[2], a[3]),
                    cvtpk(b[0], b[1]), cvtpk(b[2], b[3]) };
        *(u32x4*)(dst + off) = v;
    }
}

// ---------------------------------------------------------------------------
// Kernel 1: QKV projections, pure bf16, m97 structure + XOR bank swizzle.
// Epilogue writes MFMA-fragment-linear layouts (coalesced retention loads).
// ---------------------------------------------------------------------------
__global__ __launch_bounds__(256) void qkv_bf16(
    const unsigned short* __restrict__ xb,
    const unsigned short* __restrict__ wqb, const unsigned short* __restrict__ wkb,
    const unsigned short* __restrict__ wvb,
    unsigned short* __restrict__ qfr, unsigned short* __restrict__ kfr,
    unsigned short* __restrict__ vfr)
{
    __shared__ unsigned short sR[128 * 64];
    __shared__ unsigned short sL[128 * 64];

    const int z = blockIdx.z;
    const unsigned short* W = (z == 0) ? wqb : (z == 1) ? wkb : wvb;
    const unsigned short* Rs = (z < 2) ? xb : W;
    const unsigned short* Ls = (z < 2) ? W : xb;
    const int rblk = (z < 2) ? blockIdx.x : blockIdx.y;
    const int lblk = (z < 2) ? blockIdx.y : blockIdx.x;

    const int tid = threadIdx.x;
    const int l = tid & 63, w = tid >> 6;
    const int lrow = l & 15, koff4 = (l >> 4) * 4;
    const int swz = lrow & 7;
    const int wrow = (w >> 1) * 64, wcol = (w & 1) * 64;

    f32x4 acc[4][4] = {};

    const int srow = w * 32 + (l >> 3);
    const int scol = ((l & 7) ^ ((l >> 3) & 7)) * 8;
    const unsigned short* gR = Rs + (size_t)(rblk * 128 + srow) * 1024 + scol;
    const unsigned short* gL = Ls + (size_t)(lblk * 128 + srow) * 1024 + scol;
    unsigned short* lRb = sR + (w * 32) * 64;
    unsigned short* lLb = sL + (w * 32) * 64;

    for (int kk = 0; kk < 1024; kk += 64) {
        #pragma unroll
        for (int p = 0; p < 4; ++p) {
            gl16(gR + (size_t)p * 8 * 1024 + kk, lRb + p * 512);
            gl16(gL + (size_t)p * 8 * 1024 + kk, lLb + p * 512);
        }
        __syncthreads();
        #pragma unroll
        for (int kt = 0; kt < 2; ++kt) {
            bf16x8 aL[4], bR[4];
            #pragma unroll
            for (int f = 0; f < 4; ++f) {
                const int co = ((kt * 4 + (l >> 4)) ^ swz) * 8;
                aL[f] = *(const bf16x8*)&sL[(wcol + f * 16 + lrow) * 64 + co];
                bR[f] = *(const bf16x8*)&sR[(wrow + f * 16 + lrow) * 64 + co];
            }
            #pragma unroll
            for (int af = 0; af < 4; ++af)
                #pragma unroll
                for (int bf = 0; bf < 4; ++bf)
                    acc[af][bf] = mfma16(aL[af], bR[bf], acc[af][bf]);
        }
        __syncthreads();
    }

    #pragma unroll
    for (int af = 0; af < 4; ++af) {
        #pragma unroll
        for (int bf = 0; bf < 4; ++bf) {
            const int m = rblk * 128 + wrow + bf * 16 + lrow;
            const int n0 = lblk * 128 + wcol + af * 16 + koff4;
            f32x4 v = acc[af][bf];
            unsigned p0 = cvtpk(v[0], v[1]), p1 = cvtpk(v[2], v[3]);
            u16x4 val = { (unsigned short)(p0 & 0xffff), (unsigned short)(p0 >> 16),
                          (unsigned short)(p1 & 0xffff), (unsigned short)(p1 >> 16) };
            if (z < 2) {
                const int bq = m >> 11, s = m & 2047;
                const int h2 = n0 >> 6, dd = n0 & 63;
                const size_t addr = (size_t)((bq * 16 + h2) * 64 + (s >> 5)) * 2048
                                  + (size_t)(dd >> 4) * 512 + (size_t)((dd >> 3) & 1) * 256
                                  + (size_t)(s & 31) * 8 + (dd & 7);
                unsigned short* dst = z ? kfr : qfr;
                *(u16x4*)(dst + addr) = val;
            } else {
                const int h2 = m >> 6, dd = m & 63;
                const int bq = n0 >> 11, t = n0 & 2047;
                const size_t addr = (size_t)((bq * 16 + h2) * 64 + (t >> 5)) * 2048
                                  + (size_t)((dd >> 5) * 2 + ((t >> 4) & 1)) * 512
                                  + (size_t)((t >> 3) & 1) * 256
                                  + (size_t)(dd & 31) * 8 + (t & 7);
                *(u16x4*)(vfr + addr) = val;
            }
        }
    }
}

// ---------------------------------------------------------------------------
// Kernel 2: retention, chunk-parallel. Block = 4 waves on ONE (bh,tw); each
// wave processes 1/4 of the decay-cut s-window (retention is linear in V, so
// partials sum exactly). Deterministic f32 LDS reduce, 1 barrier, no atomics.
// Critical path <= 16 iters (was 64); 8192 waves total.
// ---------------------------------------------------------------------------
__global__ __launch_bounds__(256) void retention_chunked(
    const unsigned short* __restrict__ qfr, const unsigned short* __restrict__ kfr,
    const unsigned short* __restrict__ vfr, const float* __restrict__ gammas,
    unsigned short* __restrict__ ret)
{
    __shared__ float red[3][32][64];   // 24 KB: partials of waves 1..3

    const int bid = blockIdx.x;
    const int xcd = bid & 7;
    const int idx = bid >> 3;               // 0..255
    const int bh  = (xcd << 2) | (idx & 3); // 4 heads per XCD -> ~2MB L2 set
    const int tw  = 63 - (idx >> 2);        // heavy blocks first
    const int b = bh >> 4, h = bh & 15;
    const float lg = log2f(gammas[h]);      // < 0
    const int cut_i = (int)(45.0f / (-lg));

    const int tid = threadIdx.x;
    const int l = tid & 63, w = tid >> 6;
    const int l31 = l & 31, hi = l >> 5;
    const int tw0 = tw << 5;
    const int tq = tw0 + l31;

    const size_t hbase = (size_t)((b * 16 + h) * 64) * 2048;
    const unsigned short* qfb = qfr + hbase + l * 8;
    const unsigned short* kfb = kfr + hbase + l * 8;
    const unsigned short* vfb = vfr + hbase + l * 8;

    // Q fragments (identical across the 4 waves; B operand: n=l31 -> t)
    bf16x8 qf[4];
    #pragma unroll
    for (int kt = 0; kt < 4; ++kt)
        qf[kt] = *(const bf16x8*)(qfb + (size_t)tw * 2048 + kt * 512);

    // cf[r] = gamma^(31 - crow(r)), crow = (r&3)+4*hi+8*(r>>2)
    float cf[16];
    #pragma unroll
    for (int r = 0; r < 16; ++r) {
        const int crow = (r & 3) + (hi << 2) + ((r >> 2) << 3);
        cf[r] = exp2f((float)(31 - crow) * lg);
    }

    auto ldk = [&](int sb, bf16x8* kf) {
        const unsigned short* p = kfb + (size_t)sb * 2048;
        #pragma unroll
        for (int kt = 0; kt < 4; ++kt) kf[kt] = *(const bf16x8*)(p + kt * 512);
    };
    auto ldv = [&](int sb, bf16x8* vf) {
        const unsigned short* p = vfb + (size_t)sb * 2048;
        #pragma unroll
        for (int i = 0; i < 4; ++i) vf[i] = *(const bf16x8*)(p + i * 512);
    };

    int sb_lo = tw0 - 31 - cut_i;
    sb_lo = (sb_lo <= 0) ? 0 : (sb_lo >> 5);

    // split [sb_lo, tw] into 4 chunks, wave w takes chunk w
    const int n = tw - sb_lo + 1;
    const int chunk = (n + 3) >> 2;
    const int my_lo = sb_lo + w * chunk;
    int my_hi = my_lo + chunk;               // exclusive
    if (my_hi > tw + 1) my_hi = tw + 1;

    f32x16 acc0 = {}, acc1 = {};

    if (my_lo < my_hi) {
        bf16x8 kc[4], vc[4], kn[4], vn[4];
        ldk(my_lo, kc);
        ldv(my_lo, vc);

        for (int sb = my_lo; sb < my_hi; ++sb) {
            if (sb + 1 < my_hi) { ldk(sb + 1, kn); ldv(sb + 1, vn); }
            const int s0 = sb << 5;
            // QK^T swapped: A=K (m=s), B=Q (n=t). D: col=t=l31, row=s=crow(r).
            f32x16 sc = {};
            #pragma unroll
            for (int kt = 0; kt < 4; ++kt) sc = mfma32(kc[kt], qf[kt], sc);

            const float rowf = 0.125f * exp2f((float)(tq - s0 - 31) * lg);
            const bool diag = (sb == tw);
            const int dtq = tq - s0;
            float wv_[16];
            #pragma unroll
            for (int r = 0; r < 16; ++r) {
                float t_ = sc[r] * rowf * cf[r];
                if (diag) {
                    const int crow = (r & 3) + (hi << 2) + ((r >> 2) << 3);
                    t_ = (dtq >= crow) ? t_ : 0.0f;
                }
                wv_[r] = t_;
            }
            unsigned pk_[8];
            #pragma unroll
            for (int i = 0; i < 8; ++i) pk_[i] = cvtpk(wv_[2 * i], wv_[2 * i + 1]);
            asm("v_permlane32_swap_b32 %0, %1" : "+v"(pk_[0]), "+v"(pk_[2]));
            asm("v_permlane32_swap_b32 %0, %1" : "+v"(pk_[1]), "+v"(pk_[3]));
            asm("v_permlane32_swap_b32 %0, %1" : "+v"(pk_[4]), "+v"(pk_[6]));
            asm("v_permlane32_swap_b32 %0, %1" : "+v"(pk_[5]), "+v"(pk_[7]));
            u32x4 f0v = { pk_[0], pk_[1], pk_[2], pk_[3] };
            u32x4 f1v = { pk_[4], pk_[5], pk_[6], pk_[7] };
            const bf16x8 pa0 = __builtin_bit_cast(bf16x8, f0v);
            const bf16x8 pa1 = __builtin_bit_cast(bf16x8, f1v);
            // PV: A=P (m=t), B=V (n=d, k=s)
            acc0 = mfma32(pa0, vc[0], acc0);
            acc0 = mfma32(pa1, vc[1], acc0);
            acc1 = mfma32(pa0, vc[2], acc1);
            acc1 = mfma32(pa1, vc[3], acc1);

            if (sb + 1 < my_hi) {
                #pragma unroll
                for (int i = 0; i < 4; ++i) { kc[i] = kn[i]; vc[i] = vn[i]; }
            }
        }
    }

    // deterministic partial reduce: waves 1..3 -> LDS, wave 0 sums + stores
    if (w > 0) {
        #pragma unroll
        for (int r = 0; r < 16; ++r) {
            red[w - 1][r][l]      = acc0[r];
            red[w - 1][r + 16][l] = acc1[r];
        }
    }
    __syncthreads();
    if (w == 0) {
        #pragma unroll
        for (int j = 0; j < 3; ++j)
            #pragma unroll
            for (int r = 0; r < 16; ++r) {
                acc0[r] += red[j][r][l];
                acc1[r] += red[j][r + 16][l];
            }
        #pragma unroll
        for (int r = 0; r < 16; ++r) {
            const int tl = (r & 3) + (hi << 2) + ((r >> 2) << 3);
            unsigned short* dst = ret + (size_t)(b * 2048 + tw0 + tl) * 1024 + h * 64 + l31;
            dst[0]  = f2bf(acc0[r]);
            dst[32] = f2bf(acc1[r]);
        }
    }
}

// ---------------------------------------------------------------------------
// Kernel 3: out = ret @ wo.T, bf16 in / f32 out, same swizzled m97 structure.
// ---------------------------------------------------------------------------
__global__ __launch_bounds__(256) void out_bf16(
    const unsigned short* __restrict__ ret, const unsigned short* __restrict__ wob,
    float* __restrict__ out)
{
    __shared__ unsigned short sR[128 * 64];
    __shared__ unsigned short sL[128 * 64];

    const int rblk = blockIdx.x;
    const int lblk = blockIdx.y;

    const int tid = threadIdx.x;
    const int l = tid & 63, w = tid >> 6;
    const int lrow = l & 15, koff4 = (l >> 4) * 4;
    const int swz = lrow & 7;
    const int wrow = (w >> 1) * 64, wcol = (w & 1) * 64;

    f32x4 acc[4][4] = {};

    const int srow = w * 32 + (l >> 3);
    const int scol = ((l & 7) ^ ((l >> 3) & 7)) * 8;
    const unsigned short* gR = ret + (size_t)(rblk * 128 + srow) * 1024 + scol;
    const unsigned short* gL = wob + (size_t)(lblk * 128 + srow) * 1024 + scol;
    unsigned short* lRb = sR + (w * 32) * 64;
    unsigned short* lLb = sL + (w * 32) * 64;

    for (int kk = 0; kk < 1024; kk += 64) {
        #pragma unroll
        for (int p = 0; p < 4; ++p) {
            gl16(gR + (size_t)p * 8 * 1024 + kk, lRb + p * 512);
            gl16(gL + (size_t)p * 8 * 1024 + kk, lLb + p * 512);
        }
        __syncthreads();
        #pragma unroll
        for (int kt = 0; kt < 2; ++kt) {
            bf16x8 aL[4], bR[4];
            #pragma unroll
            for (int f = 0; f < 4; ++f) {
                const int co = ((kt * 4 + (l >> 4)) ^ swz) * 8;
                aL[f] = *(const bf16x8*)&sL[(wcol + f * 16 + lrow) * 64 + co];
                bR[f] = *(const bf16x8*)&sR[(wrow + f * 16 + lrow) * 64 + co];
            }
            #pragma unroll
            for (int af = 0; af < 4; ++af)
                #pragma unroll
                for (int bf = 0; bf < 4; ++bf)
                    acc[af][bf] = mfma16(aL[af], bR[bf], acc[af][bf]);
        }
        __syncthreads();
    }

    #pragma unroll
    for (int af = 0; af < 4; ++af)
        #pragma unroll
        for (int bf = 0; bf < 4; ++bf) {
            const int m = rblk * 128 + wrow + bf * 16 + lrow;
            const int n0 = lblk * 128 + wcol + af * 16 + koff4;
            *(f32x4*)(out + (size_t)m * 1024 + n0) = acc[af][bf];
        }
}

extern "C" void kernel_launch(void* const* d_in, const int* in_sizes, int n_in,
                              void* d_out, int out_size, void* d_ws, size_t ws_size,
                              hipStream_t stream) {
    const float* x      = (const float*)d_in[0];
    const float* wq     = (const float*)d_in[1];
    const float* wk     = (const float*)d_in[2];
    const float* wv     = (const float*)d_in[3];
    const float* wo     = (const float*)d_in[4];
    const float* gammas = (const float*)d_in[5];
    float* out = (float*)d_out;

    unsigned short* ws = (unsigned short*)d_ws;
    unsigned short* qf  = ws;
    unsigned short* kf  = ws + (size_t)4 * 1024 * 1024;
    unsigned short* vf  = ws + (size_t)8 * 1024 * 1024;
    unsigned short* ret = ws + (size_t)12 * 1024 * 1024;   // also xb (dead after qkv)
    unsigned short* xb  = ret;
    unsigned short* wqb = ws + (size_t)16 * 1024 * 1024;
    unsigned short* wkb = ws + (size_t)17 * 1024 * 1024;
    unsigned short* wvb = ws + (size_t)18 * 1024 * 1024;
    unsigned short* wob = ws + (size_t)19 * 1024 * 1024;

    convert_bf16<<<1024, 256, 0, stream>>>(x, wq, wk, wv, wo, xb, wqb, wkb, wvb, wob);
    qkv_bf16<<<dim3(32, 8, 3), 256, 0, stream>>>(xb, wqb, wkb, wvb, qf, kf, vf);
    retention_chunked<<<2048, 256, 0, stream>>>(qf, kf, vf, gammas, ret);
    out_bf16<<<dim3(32, 8), 256, 0, stream>>>(ret, wob, out);
}

// Round 9
// 94.602 us; speedup vs baseline: 1.4708x; 1.0198x over previous
//
#include <hip/hip_runtime.h>

// MultiScaleRetention on MI355X (gfx950)
// B=2, L=2048, D=1024, H=16, hd=64. fp32 in/out, bf16 MFMA internally.
//
// ws layout (ushort elems), 40 MB total:
//   qf[4M] | kf[4M] | vf[4M] | ret/xb[4M] (aliased) | wqb|wkb|wvb|wob [1M each]
//   qf,kf: fragment-linear [(b*16+h)*64+sb][kt:4][lane:64][8]
//   vf:    fragment-linear [(b*16+h)*64+sb][i:4][lane:64][8]
//   ret,xb: [B*L][1024] row-major bf16

typedef __attribute__((ext_vector_type(8))) short bf16x8;
typedef __attribute__((ext_vector_type(4))) float f32x4;
typedef __attribute__((ext_vector_type(16))) float f32x16;
typedef __attribute__((ext_vector_type(4))) unsigned short u16x4;
typedef __attribute__((ext_vector_type(8))) unsigned short u16x8;
typedef __attribute__((ext_vector_type(4))) unsigned int u32x4;

__device__ inline unsigned short f2bf(float f) {
    unsigned int u;
    __builtin_memcpy(&u, &f, 4);
    u += 0x7fffu + ((u >> 16) & 1u);
    return (unsigned short)(u >> 16);
}

__device__ inline f32x4 mfma16(bf16x8 a, bf16x8 b, f32x4 c) {
    return __builtin_amdgcn_mfma_f32_16x16x32_bf16(a, b, c, 0, 0, 0);
}
__device__ inline f32x16 mfma32(bf16x8 a, bf16x8 b, f32x16 c) {
    return __builtin_amdgcn_mfma_f32_32x32x16_bf16(a, b, c, 0, 0, 0);
}

__device__ inline void gl16(const unsigned short* g, unsigned short* l) {
    __builtin_amdgcn_global_load_lds(
        (const __attribute__((address_space(1))) unsigned int*)g,
        (__attribute__((address_space(3))) unsigned int*)l,
        16, 0, 0);
}

__device__ inline unsigned cvtpk(float lo, float hi) {
    unsigned r;
    asm("v_cvt_pk_bf16_f32 %0, %1, %2" : "=v"(r) : "v"(lo), "v"(hi));
    return r;
}

// ---------------------------------------------------------------------------
// Kernel 0: f32 -> bf16 conversion of x and the four weight matrices.
// ---------------------------------------------------------------------------
__global__ __launch_bounds__(256) void convert_bf16(
    const float* __restrict__ x,
    const float* __restrict__ wq, const float* __restrict__ wk,
    const float* __restrict__ wv, const float* __restrict__ wo,
    unsigned short* __restrict__ xb,
    unsigned short* __restrict__ wqb, unsigned short* __restrict__ wkb,
    unsigned short* __restrict__ wvb, unsigned short* __restrict__ wob)
{
    int cid = blockIdx.x * 256 + threadIdx.x;
    #pragma unroll
    for (int it = 0; it < 4; ++it, cid += 262144) {
        const float* src;
        unsigned short* dst;
        size_t off;
        if (cid < 524288) {
            src = x; dst = xb; off = (size_t)cid * 8;
        } else {
            const int t = cid - 524288;
            const int seg = t >> 17;
            off = (size_t)(t & 131071) * 8;
            src = seg == 0 ? wq : seg == 1 ? wk : seg == 2 ? wv : wo;
            dst = seg == 0 ? wqb : seg == 1 ? wkb : seg == 2 ? wvb : wob;
        }
        f32x4 a = *(const f32x4*)(src + off);
        f32x4 b = *(const f32x4*)(src + off + 4);
        u32x4 v = { cvtpk(a[0], a[1]), cvtpk(a[2], a[3]),
                    cvtpk(b[0], b[1]), cvtpk(b[2], b[3]) };
        *(u32x4*)(dst + off) = v;
    }
}

// ---------------------------------------------------------------------------
// Kernel 1: QKV projections, pure bf16, m97 structure + XOR bank swizzle.
// Epilogue writes MFMA-fragment-linear layouts (coalesced retention loads).
// ---------------------------------------------------------------------------
__global__ __launch_bounds__(256) void qkv_bf16(
    const unsigned short* __restrict__ xb,
    const unsigned short* __restrict__ wqb, const unsigned short* __restrict__ wkb,
    const unsigned short* __restrict__ wvb,
    unsigned short* __restrict__ qfr, unsigned short* __restrict__ kfr,
    unsigned short* __restrict__ vfr)
{
    __shared__ unsigned short sR[128 * 64];
    __shared__ unsigned short sL[128 * 64];

    const int z = blockIdx.z;
    const unsigned short* W = (z == 0) ? wqb : (z == 1) ? wkb : wvb;
    const unsigned short* Rs = (z < 2) ? xb : W;
    const unsigned short* Ls = (z < 2) ? W : xb;
    const int rblk = (z < 2) ? blockIdx.x : blockIdx.y;
    const int lblk = (z < 2) ? blockIdx.y : blockIdx.x;

    const int tid = threadIdx.x;
    const int l = tid & 63, w = tid >> 6;
    const int lrow = l & 15, koff4 = (l >> 4) * 4;
    const int swz = lrow & 7;
    const int wrow = (w >> 1) * 64, wcol = (w & 1) * 64;

    f32x4 acc[4][4] = {};

    const int srow = w * 32 + (l >> 3);
    const int scol = ((l & 7) ^ ((l >> 3) & 7)) * 8;
    const unsigned short* gR = Rs + (size_t)(rblk * 128 + srow) * 1024 + scol;
    const unsigned short* gL = Ls + (size_t)(lblk * 128 + srow) * 1024 + scol;
    unsigned short* lRb = sR + (w * 32) * 64;
    unsigned short* lLb = sL + (w * 32) * 64;

    for (int kk = 0; kk < 1024; kk += 64) {
        #pragma unroll
        for (int p = 0; p < 4; ++p) {
            gl16(gR + (size_t)p * 8 * 1024 + kk, lRb + p * 512);
            gl16(gL + (size_t)p * 8 * 1024 + kk, lLb + p * 512);
        }
        __syncthreads();
        #pragma unroll
        for (int kt = 0; kt < 2; ++kt) {
            bf16x8 aL[4], bR[4];
            #pragma unroll
            for (int f = 0; f < 4; ++f) {
                const int co = ((kt * 4 + (l >> 4)) ^ swz) * 8;
                aL[f] = *(const bf16x8*)&sL[(wcol + f * 16 + lrow) * 64 + co];
                bR[f] = *(const bf16x8*)&sR[(wrow + f * 16 + lrow) * 64 + co];
            }
            #pragma unroll
            for (int af = 0; af < 4; ++af)
                #pragma unroll
                for (int bf = 0; bf < 4; ++bf)
                    acc[af][bf] = mfma16(aL[af], bR[bf], acc[af][bf]);
        }
        __syncthreads();
    }

    #pragma unroll
    for (int af = 0; af < 4; ++af) {
        #pragma unroll
        for (int bf = 0; bf < 4; ++bf) {
            const int m = rblk * 128 + wrow + bf * 16 + lrow;
            const int n0 = lblk * 128 + wcol + af * 16 + koff4;
            f32x4 v = acc[af][bf];
            unsigned p0 = cvtpk(v[0], v[1]), p1 = cvtpk(v[2], v[3]);
            u16x4 val = { (unsigned short)(p0 & 0xffff), (unsigned short)(p0 >> 16),
                          (unsigned short)(p1 & 0xffff), (unsigned short)(p1 >> 16) };
            if (z < 2) {
                const int bq = m >> 11, s = m & 2047;
                const int h2 = n0 >> 6, dd = n0 & 63;
                const size_t addr = (size_t)((bq * 16 + h2) * 64 + (s >> 5)) * 2048
                                  + (size_t)(dd >> 4) * 512 + (size_t)((dd >> 3) & 1) * 256
                                  + (size_t)(s & 31) * 8 + (dd & 7);
                unsigned short* dst = z ? kfr : qfr;
                *(u16x4*)(dst + addr) = val;
            } else {
                const int h2 = m >> 6, dd = m & 63;
                const int bq = n0 >> 11, t = n0 & 2047;
                const size_t addr = (size_t)((bq * 16 + h2) * 64 + (t >> 5)) * 2048
                                  + (size_t)((dd >> 5) * 2 + ((t >> 4) & 1)) * 512
                                  + (size_t)((t >> 3) & 1) * 256
                                  + (size_t)(dd & 31) * 8 + (t & 7);
                *(u16x4*)(vfr + addr) = val;
            }
        }
    }
}

// ---------------------------------------------------------------------------
// Kernel 2: retention, paired tiles for uniform block duration.
// Block = 4 waves, handles tiles (63-p) then (p) of one (b,h): window lengths
// sum to ~const per head -> grid 1024 = exactly the 4-blocks/CU residency cap,
// no drain-down. Per tile: 4-way s-chunked, deterministic LDS f32 reduce.
// Micro: rowf multiply-recurrence (no per-iter exp2f), diag peeled into a
// wave-uniform branch, s_setprio around MFMA clusters.
// ---------------------------------------------------------------------------
__global__ __launch_bounds__(256) void retention_paired(
    const unsigned short* __restrict__ qfr, const unsigned short* __restrict__ kfr,
    const unsigned short* __restrict__ vfr, const float* __restrict__ gammas,
    unsigned short* __restrict__ ret)
{
    __shared__ float red[3][32][64];   // 24 KB, reused for both tiles

    const int bid = blockIdx.x;
    const int xcd = bid & 7;
    const int j = bid >> 3;                 // 0..127
    const int bh  = (xcd << 2) | (j & 3);   // 4 heads per XCD -> ~2MB L2 set
    const int p = j >> 2;                   // 0..31 -> tiles {63-p, p}
    const int b = bh >> 4, h = bh & 15;
    const float lg = log2f(gammas[h]);      // < 0
    const int cut_i = (int)(45.0f / (-lg));
    const float gi32 = exp2f(-32.0f * lg);  // gamma^-32

    const int tid = threadIdx.x;
    const int l = tid & 63, w = tid >> 6;
    const int l31 = l & 31, hi = l >> 5;

    const size_t hbase = (size_t)((b * 16 + h) * 64) * 2048;
    const unsigned short* qfb = qfr + hbase + l * 8;
    const unsigned short* kfb = kfr + hbase + l * 8;
    const unsigned short* vfb = vfr + hbase + l * 8;

    // cf[r] = gamma^(31 - crow(r)), crow = (r&3)+4*hi+8*(r>>2)
    float cf[16];
    #pragma unroll
    for (int r = 0; r < 16; ++r) {
        const int crow = (r & 3) + (hi << 2) + ((r >> 2) << 3);
        cf[r] = exp2f((float)(31 - crow) * lg);
    }

    auto ldk = [&](int sb, bf16x8* kf) {
        const unsigned short* ptr = kfb + (size_t)sb * 2048;
        #pragma unroll
        for (int kt = 0; kt < 4; ++kt) kf[kt] = *(const bf16x8*)(ptr + kt * 512);
    };
    auto ldv = [&](int sb, bf16x8* vf) {
        const unsigned short* ptr = vfb + (size_t)sb * 2048;
        #pragma unroll
        for (int i = 0; i < 4; ++i) vf[i] = *(const bf16x8*)(ptr + i * 512);
    };

    auto do_tile = [&](int tw) {
        const int tw0 = tw << 5;
        const int tq = tw0 + l31;

        // Q fragments (B operand: n=l31 -> t)
        bf16x8 qf[4];
        #pragma unroll
        for (int kt = 0; kt < 4; ++kt)
            qf[kt] = *(const bf16x8*)(qfb + (size_t)tw * 2048 + kt * 512);

        int sb_lo = tw0 - 31 - cut_i;
        sb_lo = (sb_lo <= 0) ? 0 : (sb_lo >> 5);

        const int n = tw - sb_lo + 1;
        const int chunk = (n + 3) >> 2;
        const int my_lo = sb_lo + w * chunk;
        int my_hi = my_lo + chunk;
        if (my_hi > tw + 1) my_hi = tw + 1;

        f32x16 acc0 = {}, acc1 = {};

        if (my_lo < my_hi) {
            float rowf = 0.125f * exp2f((float)(tq - (my_lo << 5) - 31) * lg);
            bf16x8 kc[4], vc[4], kn[4], vn[4];
            ldk(my_lo, kc);
            ldv(my_lo, vc);

            for (int sb = my_lo; sb < my_hi; ++sb) {
                if (sb + 1 < my_hi) { ldk(sb + 1, kn); ldv(sb + 1, vn); }
                // QK^T swapped: A=K (m=s), B=Q (n=t). D: col=t=l31, row=s=crow(r)
                f32x16 sc = {};
                __builtin_amdgcn_s_setprio(1);
                #pragma unroll
                for (int kt = 0; kt < 4; ++kt) sc = mfma32(kc[kt], qf[kt], sc);
                __builtin_amdgcn_s_setprio(0);

                float wv_[16];
                if (sb == tw) {            // wave-uniform branch: diag tile
                    const int dtq = tq - (sb << 5);
                    #pragma unroll
                    for (int r = 0; r < 16; ++r) {
                        const int crow = (r & 3) + (hi << 2) + ((r >> 2) << 3);
                        float t_ = sc[r] * rowf * cf[r];
                        wv_[r] = (dtq >= crow) ? t_ : 0.0f;
                    }
                } else {
                    #pragma unroll
                    for (int r = 0; r < 16; ++r)
                        wv_[r] = sc[r] * rowf * cf[r];
                }
                unsigned pk_[8];
                #pragma unroll
                for (int i = 0; i < 8; ++i) pk_[i] = cvtpk(wv_[2 * i], wv_[2 * i + 1]);
                asm("v_permlane32_swap_b32 %0, %1" : "+v"(pk_[0]), "+v"(pk_[2]));
                asm("v_permlane32_swap_b32 %0, %1" : "+v"(pk_[1]), "+v"(pk_[3]));
                asm("v_permlane32_swap_b32 %0, %1" : "+v"(pk_[4]), "+v"(pk_[6]));
                asm("v_permlane32_swap_b32 %0, %1" : "+v"(pk_[5]), "+v"(pk_[7]));
                u32x4 f0v = { pk_[0], pk_[1], pk_[2], pk_[3] };
                u32x4 f1v = { pk_[4], pk_[5], pk_[6], pk_[7] };
                const bf16x8 pa0 = __builtin_bit_cast(bf16x8, f0v);
                const bf16x8 pa1 = __builtin_bit_cast(bf16x8, f1v);
                // PV: A=P (m=t), B=V (n=d, k=s)
                __builtin_amdgcn_s_setprio(1);
                acc0 = mfma32(pa0, vc[0], acc0);
                acc0 = mfma32(pa1, vc[1], acc0);
                acc1 = mfma32(pa0, vc[2], acc1);
                acc1 = mfma32(pa1, vc[3], acc1);
                __builtin_amdgcn_s_setprio(0);

                rowf *= gi32;
                if (sb + 1 < my_hi) {
                    #pragma unroll
                    for (int i = 0; i < 4; ++i) { kc[i] = kn[i]; vc[i] = vn[i]; }
                }
            }
        }

        // deterministic partial reduce: waves 1..3 -> LDS, wave 0 sums + stores
        if (w > 0) {
            #pragma unroll
            for (int r = 0; r < 16; ++r) {
                red[w - 1][r][l]      = acc0[r];
                red[w - 1][r + 16][l] = acc1[r];
            }
        }
        __syncthreads();
        if (w == 0) {
            #pragma unroll
            for (int jj = 0; jj < 3; ++jj)
                #pragma unroll
                for (int r = 0; r < 16; ++r) {
                    acc0[r] += red[jj][r][l];
                    acc1[r] += red[jj][r + 16][l];
                }
            #pragma unroll
            for (int r = 0; r < 16; ++r) {
                const int tl = (r & 3) + (hi << 2) + ((r >> 2) << 3);
                unsigned short* dst = ret + (size_t)(b * 2048 + tw0 + tl) * 1024 + h * 64 + l31;
                dst[0]  = f2bf(acc0[r]);
                dst[32] = f2bf(acc1[r]);
            }
        }
        __syncthreads();   // protect red before next tile reuses it
    };

    do_tile(63 - p);   // heavy member first
    do_tile(p);
}

// ---------------------------------------------------------------------------
// Kernel 3: out = ret @ wo.T, bf16 in / f32 out, same swizzled m97 structure.
// ---------------------------------------------------------------------------
__global__ __launch_bounds__(256) void out_bf16(
    const unsigned short* __restrict__ ret, const unsigned short* __restrict__ wob,
    float* __restrict__ out)
{
    __shared__ unsigned short sR[128 * 64];
    __shared__ unsigned short sL[128 * 64];

    const int rblk = blockIdx.x;
    const int lblk = blockIdx.y;

    const int tid = threadIdx.x;
    const int l = tid & 63, w = tid >> 6;
    const int lrow = l & 15, koff4 = (l >> 4) * 4;
    const int swz = lrow & 7;
    const int wrow = (w >> 1) * 64, wcol = (w & 1) * 64;

    f32x4 acc[4][4] = {};

    const int srow = w * 32 + (l >> 3);
    const int scol = ((l & 7) ^ ((l >> 3) & 7)) * 8;
    const unsigned short* gR = ret + (size_t)(rblk * 128 + srow) * 1024 + scol;
    const unsigned short* gL = wob + (size_t)(lblk * 128 + srow) * 1024 + scol;
    unsigned short* lRb = sR + (w * 32) * 64;
    unsigned short* lLb = sL + (w * 32) * 64;

    for (int kk = 0; kk < 1024; kk += 64) {
        #pragma unroll
        for (int p = 0; p < 4; ++p) {
            gl16(gR + (size_t)p * 8 * 1024 + kk, lRb + p * 512);
            gl16(gL + (size_t)p * 8 * 1024 + kk, lLb + p * 512);
        }
        __syncthreads();
        #pragma unroll
        for (int kt = 0; kt < 2; ++kt) {
            bf16x8 aL[4], bR[4];
            #pragma unroll
            for (int f = 0; f < 4; ++f) {
                const int co = ((kt * 4 + (l >> 4)) ^ swz) * 8;
                aL[f] = *(const bf16x8*)&sL[(wcol + f * 16 + lrow) * 64 + co];
                bR[f] = *(const bf16x8*)&sR[(wrow + f * 16 + lrow) * 64 + co];
            }
            #pragma unroll
            for (int af = 0; af < 4; ++af)
                #pragma unroll
                for (int bf = 0; bf < 4; ++bf)
                    acc[af][bf] = mfma16(aL[af], bR[bf], acc[af][bf]);
        }
        __syncthreads();
    }

    #pragma unroll
    for (int af = 0; af < 4; ++af)
        #pragma unroll
        for (int bf = 0; bf < 4; ++bf) {
            const int m = rblk * 128 + wrow + bf * 16 + lrow;
            const int n0 = lblk * 128 + wcol + af * 16 + koff4;
            *(f32x4*)(out + (size_t)m * 1024 + n0) = acc[af][bf];
        }
}

extern "C" void kernel_launch(void* const* d_in, const int* in_sizes, int n_in,
                              void* d_out, int out_size, void* d_ws, size_t ws_size,
                              hipStream_t stream) {
    const float* x      = (const float*)d_in[0];
    const float* wq     = (const float*)d_in[1];
    const float* wk     = (const float*)d_in[2];
    const float* wv     = (const float*)d_in[3];
    const float* wo     = (const float*)d_in[4];
    const float* gammas = (const float*)d_in[5];
    float* out = (float*)d_out;

    unsigned short* ws = (unsigned short*)d_ws;
    unsigned short* qf  = ws;
    unsigned short* kf  = ws + (size_t)4 * 1024 * 1024;
    unsigned short* vf  = ws + (size_t)8 * 1024 * 1024;
    unsigned short* ret = ws + (size_t)12 * 1024 * 1024;   // also xb (dead after qkv)
    unsigned short* xb  = ret;
    unsigned short* wqb = ws + (size_t)16 * 1024 * 1024;
    unsigned short* wkb = ws + (size_t)17 * 1024 * 1024;
    unsigned short* wvb = ws + (size_t)18 * 1024 * 1024;
    unsigned short* wob = ws + (size_t)19 * 1024 * 1024;

    convert_bf16<<<1024, 256, 0, stream>>>(x, wq, wk, wv, wo, xb, wqb, wkb, wvb, wob);
    qkv_bf16<<<dim3(32, 8, 3), 256, 0, stream>>>(xb, wqb, wkb, wvb, qf, kf, vf);
    retention_paired<<<1024, 256, 0, stream>>>(qf, kf, vf, gammas, ret);
    out_bf16<<<dim3(32, 8), 256, 0, stream>>>(ret, wob, out);
}

// Round 10
// 91.111 us; speedup vs baseline: 1.5272x; 1.0383x over previous
//
#include <hip/hip_runtime.h>

// MultiScaleRetention on MI355X (gfx950)
// B=2, L=2048, D=1024, H=16, hd=64. fp32 in/out, bf16 MFMA internally.
//
// ws layout (ushort elems), 40 MB total:
//   qf[4M] | kf[4M] | vf[4M] | ret/xb[4M] (aliased) | wqb|wkb|wvb|wob [1M each]
//   qf,kf: fragment-linear [(b*16+h)*64+sb][kt:4][lane:64][8]
//   vf:    fragment-linear [(b*16+h)*64+sb][i:4][lane:64][8]
//   ret,xb: [B*L][1024] row-major bf16

typedef __attribute__((ext_vector_type(8))) short bf16x8;
typedef __attribute__((ext_vector_type(4))) float f32x4;
typedef __attribute__((ext_vector_type(16))) float f32x16;
typedef __attribute__((ext_vector_type(4))) unsigned short u16x4;
typedef __attribute__((ext_vector_type(8))) unsigned short u16x8;
typedef __attribute__((ext_vector_type(4))) unsigned int u32x4;

__device__ inline unsigned short f2bf(float f) {
    unsigned int u;
    __builtin_memcpy(&u, &f, 4);
    u += 0x7fffu + ((u >> 16) & 1u);
    return (unsigned short)(u >> 16);
}

__device__ inline f32x4 mfma16(bf16x8 a, bf16x8 b, f32x4 c) {
    return __builtin_amdgcn_mfma_f32_16x16x32_bf16(a, b, c, 0, 0, 0);
}
__device__ inline f32x16 mfma32(bf16x8 a, bf16x8 b, f32x16 c) {
    return __builtin_amdgcn_mfma_f32_32x32x16_bf16(a, b, c, 0, 0, 0);
}

__device__ inline void gl16(const unsigned short* g, unsigned short* l) {
    __builtin_amdgcn_global_load_lds(
        (const __attribute__((address_space(1))) unsigned int*)g,
        (__attribute__((address_space(3))) unsigned int*)l,
        16, 0, 0);
}

__device__ inline unsigned cvtpk(float lo, float hi) {
    unsigned r;
    asm("v_cvt_pk_bf16_f32 %0, %1, %2" : "=v"(r) : "v"(lo), "v"(hi));
    return r;
}

// ---------------------------------------------------------------------------
// Kernel 0: f32 -> bf16 conversion of x and the four weight matrices.
// ---------------------------------------------------------------------------
__global__ __launch_bounds__(256) void convert_bf16(
    const float* __restrict__ x,
    const float* __restrict__ wq, const float* __restrict__ wk,
    const float* __restrict__ wv, const float* __restrict__ wo,
    unsigned short* __restrict__ xb,
    unsigned short* __restrict__ wqb, unsigned short* __restrict__ wkb,
    unsigned short* __restrict__ wvb, unsigned short* __restrict__ wob)
{
    int cid = blockIdx.x * 256 + threadIdx.x;
    #pragma unroll
    for (int it = 0; it < 4; ++it, cid += 262144) {
        const float* src;
        unsigned short* dst;
        size_t off;
        if (cid < 524288) {
            src = x; dst = xb; off = (size_t)cid * 8;
        } else {
            const int t = cid - 524288;
            const int seg = t >> 17;
            off = (size_t)(t & 131071) * 8;
            src = seg == 0 ? wq : seg == 1 ? wk : seg == 2 ? wv : wo;
            dst = seg == 0 ? wqb : seg == 1 ? wkb : seg == 2 ? wvb : wob;
        }
        f32x4 a = *(const f32x4*)(src + off);
        f32x4 b = *(const f32x4*)(src + off + 4);
        u32x4 v = { cvtpk(a[0], a[1]), cvtpk(a[2], a[3]),
                    cvtpk(b[0], b[1]), cvtpk(b[2], b[3]) };
        *(u32x4*)(dst + off) = v;
    }
}

// ---------------------------------------------------------------------------
// Kernel 1: QKV projections, pure bf16, m97 structure + XOR bank swizzle.
// Epilogue writes MFMA-fragment-linear layouts (coalesced retention loads).
// ---------------------------------------------------------------------------
__global__ __launch_bounds__(256) void qkv_bf16(
    const unsigned short* __restrict__ xb,
    const unsigned short* __restrict__ wqb, const unsigned short* __restrict__ wkb,
    const unsigned short* __restrict__ wvb,
    unsigned short* __restrict__ qfr, unsigned short* __restrict__ kfr,
    unsigned short* __restrict__ vfr)
{
    __shared__ unsigned short sR[128 * 64];
    __shared__ unsigned short sL[128 * 64];

    const int z = blockIdx.z;
    const unsigned short* W = (z == 0) ? wqb : (z == 1) ? wkb : wvb;
    const unsigned short* Rs = (z < 2) ? xb : W;
    const unsigned short* Ls = (z < 2) ? W : xb;
    const int rblk = (z < 2) ? blockIdx.x : blockIdx.y;
    const int lblk = (z < 2) ? blockIdx.y : blockIdx.x;

    const int tid = threadIdx.x;
    const int l = tid & 63, w = tid >> 6;
    const int lrow = l & 15, koff4 = (l >> 4) * 4;
    const int swz = lrow & 7;
    const int wrow = (w >> 1) * 64, wcol = (w & 1) * 64;

    f32x4 acc[4][4] = {};

    const int srow = w * 32 + (l >> 3);
    const int scol = ((l & 7) ^ ((l >> 3) & 7)) * 8;
    const unsigned short* gR = Rs + (size_t)(rblk * 128 + srow) * 1024 + scol;
    const unsigned short* gL = Ls + (size_t)(lblk * 128 + srow) * 1024 + scol;
    unsigned short* lRb = sR + (w * 32) * 64;
    unsigned short* lLb = sL + (w * 32) * 64;

    for (int kk = 0; kk < 1024; kk += 64) {
        #pragma unroll
        for (int p = 0; p < 4; ++p) {
            gl16(gR + (size_t)p * 8 * 1024 + kk, lRb + p * 512);
            gl16(gL + (size_t)p * 8 * 1024 + kk, lLb + p * 512);
        }
        __syncthreads();
        #pragma unroll
        for (int kt = 0; kt < 2; ++kt) {
            bf16x8 aL[4], bR[4];
            #pragma unroll
            for (int f = 0; f < 4; ++f) {
                const int co = ((kt * 4 + (l >> 4)) ^ swz) * 8;
                aL[f] = *(const bf16x8*)&sL[(wcol + f * 16 + lrow) * 64 + co];
                bR[f] = *(const bf16x8*)&sR[(wrow + f * 16 + lrow) * 64 + co];
            }
            #pragma unroll
            for (int af = 0; af < 4; ++af)
                #pragma unroll
                for (int bf = 0; bf < 4; ++bf)
                    acc[af][bf] = mfma16(aL[af], bR[bf], acc[af][bf]);
        }
        __syncthreads();
    }

    #pragma unroll
    for (int af = 0; af < 4; ++af) {
        #pragma unroll
        for (int bf = 0; bf < 4; ++bf) {
            const int m = rblk * 128 + wrow + bf * 16 + lrow;
            const int n0 = lblk * 128 + wcol + af * 16 + koff4;
            f32x4 v = acc[af][bf];
            unsigned p0 = cvtpk(v[0], v[1]), p1 = cvtpk(v[2], v[3]);
            u16x4 val = { (unsigned short)(p0 & 0xffff), (unsigned short)(p0 >> 16),
                          (unsigned short)(p1 & 0xffff), (unsigned short)(p1 >> 16) };
            if (z < 2) {
                const int bq = m >> 11, s = m & 2047;
                const int h2 = n0 >> 6, dd = n0 & 63;
                const size_t addr = (size_t)((bq * 16 + h2) * 64 + (s >> 5)) * 2048
                                  + (size_t)(dd >> 4) * 512 + (size_t)((dd >> 3) & 1) * 256
                                  + (size_t)(s & 31) * 8 + (dd & 7);
                unsigned short* dst = z ? kfr : qfr;
                *(u16x4*)(dst + addr) = val;
            } else {
                const int h2 = m >> 6, dd = m & 63;
                const int bq = n0 >> 11, t = n0 & 2047;
                const size_t addr = (size_t)((bq * 16 + h2) * 64 + (t >> 5)) * 2048
                                  + (size_t)((dd >> 5) * 2 + ((t >> 4) & 1)) * 512
                                  + (size_t)((t >> 3) & 1) * 256
                                  + (size_t)(dd & 31) * 8 + (t & 7);
                *(u16x4*)(vfr + addr) = val;
            }
        }
    }
}

// ---------------------------------------------------------------------------
// Kernel 2: retention, paired tiles + XCD work balance.
// Head weights w_h are monotone in gamma, so: b=0 pairs head x with 15-x on
// XCD x; b=1 uses the REVERSED pair order (7-x). Per-XCD totals S_x+S_{7-x}
// are within 1.6% of uniform (was 3.1x imbalance). Each CU gets one block of
// each of its XCD's 4 (b,h) at the same p -> per-CU totals ~uniform too.
// L2 working set stays 4 x 512KB = 2MB/XCD.
// ---------------------------------------------------------------------------
__global__ __launch_bounds__(256) void retention_paired(
    const unsigned short* __restrict__ qfr, const unsigned short* __restrict__ kfr,
    const unsigned short* __restrict__ vfr, const float* __restrict__ gammas,
    unsigned short* __restrict__ ret)
{
    __shared__ float red[3][32][64];   // 24 KB, reused for both tiles

    const int bid = blockIdx.x;
    const int xcd = bid & 7;
    const int j = bid >> 3;                 // 0..127
    const int m = j >> 5;                   // 0..3 head-slot on this XCD
    const int p = j & 31;                   // tile-pair index (== CU slot)
    const int b = m >> 1;
    const int pi = b ? (7 - xcd) : xcd;     // pair index, reversed for b=1
    const int h = (m & 1) ? (15 - pi) : pi;
    const float lg = log2f(gammas[h]);      // < 0
    const int cut_i = (int)(45.0f / (-lg));
    const float gi32 = exp2f(-32.0f * lg);  // gamma^-32

    const int tid = threadIdx.x;
    const int l = tid & 63, w = tid >> 6;
    const int l31 = l & 31, hi = l >> 5;

    const size_t hbase = (size_t)((b * 16 + h) * 64) * 2048;
    const unsigned short* qfb = qfr + hbase + l * 8;
    const unsigned short* kfb = kfr + hbase + l * 8;
    const unsigned short* vfb = vfr + hbase + l * 8;

    // cf[r] = gamma^(31 - crow(r)), crow = (r&3)+4*hi+8*(r>>2)
    float cf[16];
    #pragma unroll
    for (int r = 0; r < 16; ++r) {
        const int crow = (r & 3) + (hi << 2) + ((r >> 2) << 3);
        cf[r] = exp2f((float)(31 - crow) * lg);
    }

    auto ldk = [&](int sb, bf16x8* kf) {
        const unsigned short* ptr = kfb + (size_t)sb * 2048;
        #pragma unroll
        for (int kt = 0; kt < 4; ++kt) kf[kt] = *(const bf16x8*)(ptr + kt * 512);
    };
    auto ldv = [&](int sb, bf16x8* vf) {
        const unsigned short* ptr = vfb + (size_t)sb * 2048;
        #pragma unroll
        for (int i = 0; i < 4; ++i) vf[i] = *(const bf16x8*)(ptr + i * 512);
    };

    auto do_tile = [&](int tw) {
        const int tw0 = tw << 5;
        const int tq = tw0 + l31;

        // Q fragments (B operand: n=l31 -> t)
        bf16x8 qf[4];
        #pragma unroll
        for (int kt = 0; kt < 4; ++kt)
            qf[kt] = *(const bf16x8*)(qfb + (size_t)tw * 2048 + kt * 512);

        int sb_lo = tw0 - 31 - cut_i;
        sb_lo = (sb_lo <= 0) ? 0 : (sb_lo >> 5);

        const int n = tw - sb_lo + 1;
        const int chunk = (n + 3) >> 2;
        const int my_lo = sb_lo + w * chunk;
        int my_hi = my_lo + chunk;
        if (my_hi > tw + 1) my_hi = tw + 1;

        f32x16 acc0 = {}, acc1 = {};

        if (my_lo < my_hi) {
            float rowf = 0.125f * exp2f((float)(tq - (my_lo << 5) - 31) * lg);
            bf16x8 kc[4], vc[4], kn[4], vn[4];
            ldk(my_lo, kc);
            ldv(my_lo, vc);

            for (int sb = my_lo; sb < my_hi; ++sb) {
                if (sb + 1 < my_hi) { ldk(sb + 1, kn); ldv(sb + 1, vn); }
                // QK^T swapped: A=K (m=s), B=Q (n=t). D: col=t=l31, row=s=crow(r)
                f32x16 sc = {};
                __builtin_amdgcn_s_setprio(1);
                #pragma unroll
                for (int kt = 0; kt < 4; ++kt) sc = mfma32(kc[kt], qf[kt], sc);
                __builtin_amdgcn_s_setprio(0);

                float wv_[16];
                if (sb == tw) {            // wave-uniform branch: diag tile
                    const int dtq = tq - (sb << 5);
                    #pragma unroll
                    for (int r = 0; r < 16; ++r) {
                        const int crow = (r & 3) + (hi << 2) + ((r >> 2) << 3);
                        float t_ = sc[r] * rowf * cf[r];
                        wv_[r] = (dtq >= crow) ? t_ : 0.0f;
                    }
                } else {
                    #pragma unroll
                    for (int r = 0; r < 16; ++r)
                        wv_[r] = sc[r] * rowf * cf[r];
                }
                unsigned pk_[8];
                #pragma unroll
                for (int i = 0; i < 8; ++i) pk_[i] = cvtpk(wv_[2 * i], wv_[2 * i + 1]);
                asm("v_permlane32_swap_b32 %0, %1" : "+v"(pk_[0]), "+v"(pk_[2]));
                asm("v_permlane32_swap_b32 %0, %1" : "+v"(pk_[1]), "+v"(pk_[3]));
                asm("v_permlane32_swap_b32 %0, %1" : "+v"(pk_[4]), "+v"(pk_[6]));
                asm("v_permlane32_swap_b32 %0, %1" : "+v"(pk_[5]), "+v"(pk_[7]));
                u32x4 f0v = { pk_[0], pk_[1], pk_[2], pk_[3] };
                u32x4 f1v = { pk_[4], pk_[5], pk_[6], pk_[7] };
                const bf16x8 pa0 = __builtin_bit_cast(bf16x8, f0v);
                const bf16x8 pa1 = __builtin_bit_cast(bf16x8, f1v);
                // PV: A=P (m=t), B=V (n=d, k=s)
                __builtin_amdgcn_s_setprio(1);
                acc0 = mfma32(pa0, vc[0], acc0);
                acc0 = mfma32(pa1, vc[1], acc0);
                acc1 = mfma32(pa0, vc[2], acc1);
                acc1 = mfma32(pa1, vc[3], acc1);
                __builtin_amdgcn_s_setprio(0);

                rowf *= gi32;
                if (sb + 1 < my_hi) {
                    #pragma unroll
                    for (int i = 0; i < 4; ++i) { kc[i] = kn[i]; vc[i] = vn[i]; }
                }
            }
        }

        // deterministic partial reduce: waves 1..3 -> LDS, wave 0 sums + stores
        if (w > 0) {
            #pragma unroll
            for (int r = 0; r < 16; ++r) {
                red[w - 1][r][l]      = acc0[r];
                red[w - 1][r + 16][l] = acc1[r];
            }
        }
        __syncthreads();
        if (w == 0) {
            #pragma unroll
            for (int jj = 0; jj < 3; ++jj)
                #pragma unroll
                for (int r = 0; r < 16; ++r) {
                    acc0[r] += red[jj][r][l];
                    acc1[r] += red[jj][r + 16][l];
                }
            #pragma unroll
            for (int r = 0; r < 16; ++r) {
                const int tl = (r & 3) + (hi << 2) + ((r >> 2) << 3);
                unsigned short* dst = ret + (size_t)(b * 2048 + tw0 + tl) * 1024 + h * 64 + l31;
                dst[0]  = f2bf(acc0[r]);
                dst[32] = f2bf(acc1[r]);
            }
        }
        __syncthreads();   // protect red before next tile reuses it
    };

    do_tile(63 - p);   // heavy member first
    do_tile(p);
}

// ---------------------------------------------------------------------------
// Kernel 3: out = ret @ wo.T, bf16 in / f32 out, same swizzled m97 structure.
// ---------------------------------------------------------------------------
__global__ __launch_bounds__(256) void out_bf16(
    const unsigned short* __restrict__ ret, const unsigned short* __restrict__ wob,
    float* __restrict__ out)
{
    __shared__ unsigned short sR[128 * 64];
    __shared__ unsigned short sL[128 * 64];

    const int rblk = blockIdx.x;
    const int lblk = blockIdx.y;

    const int tid = threadIdx.x;
    const int l = tid & 63, w = tid >> 6;
    const int lrow = l & 15, koff4 = (l >> 4) * 4;
    const int swz = lrow & 7;
    const int wrow = (w >> 1) * 64, wcol = (w & 1) * 64;

    f32x4 acc[4][4] = {};

    const int srow = w * 32 + (l >> 3);
    const int scol = ((l & 7) ^ ((l >> 3) & 7)) * 8;
    const unsigned short* gR = ret + (size_t)(rblk * 128 + srow) * 1024 + scol;
    const unsigned short* gL = wob + (size_t)(lblk * 128 + srow) * 1024 + scol;
    unsigned short* lRb = sR + (w * 32) * 64;
    unsigned short* lLb = sL + (w * 32) * 64;

    for (int kk = 0; kk < 1024; kk += 64) {
        #pragma unroll
        for (int p = 0; p < 4; ++p) {
            gl16(gR + (size_t)p * 8 * 1024 + kk, lRb + p * 512);
            gl16(gL + (size_t)p * 8 * 1024 + kk, lLb + p * 512);
        }
        __syncthreads();
        #pragma unroll
        for (int kt = 0; kt < 2; ++kt) {
            bf16x8 aL[4], bR[4];
            #pragma unroll
            for (int f = 0; f < 4; ++f) {
                const int co = ((kt * 4 + (l >> 4)) ^ swz) * 8;
                aL[f] = *(const bf16x8*)&sL[(wcol + f * 16 + lrow) * 64 + co];
                bR[f] = *(const bf16x8*)&sR[(wrow + f * 16 + lrow) * 64 + co];
            }
            #pragma unroll
            for (int af = 0; af < 4; ++af)
                #pragma unroll
                for (int bf = 0; bf < 4; ++bf)
                    acc[af][bf] = mfma16(aL[af], bR[bf], acc[af][bf]);
        }
        __syncthreads();
    }

    #pragma unroll
    for (int af = 0; af < 4; ++af)
        #pragma unroll
        for (int bf = 0; bf < 4; ++bf) {
            const int m = rblk * 128 + wrow + bf * 16 + lrow;
            const int n0 = lblk * 128 + wcol + af * 16 + koff4;
            *(f32x4*)(out + (size_t)m * 1024 + n0) = acc[af][bf];
        }
}

extern "C" void kernel_launch(void* const* d_in, const int* in_sizes, int n_in,
                              void* d_out, int out_size, void* d_ws, size_t ws_size,
                              hipStream_t stream) {
    const float* x      = (const float*)d_in[0];
    const float* wq     = (const float*)d_in[1];
    const float* wk     = (const float*)d_in[2];
    const float* wv     = (const float*)d_in[3];
    const float* wo     = (const float*)d_in[4];
    const float* gammas = (const float*)d_in[5];
    float* out = (float*)d_out;

    unsigned short* ws = (unsigned short*)d_ws;
    unsigned short* qf  = ws;
    unsigned short* kf  = ws + (size_t)4 * 1024 * 1024;
    unsigned short* vf  = ws + (size_t)8 * 1024 * 1024;
    unsigned short* ret = ws + (size_t)12 * 1024 * 1024;   // also xb (dead after qkv)
    unsigned short* xb  = ret;
    unsigned short* wqb = ws + (size_t)16 * 1024 * 1024;
    unsigned short* wkb = ws + (size_t)17 * 1024 * 1024;
    unsigned short* wvb = ws + (size_t)18 * 1024 * 1024;
    unsigned short* wob = ws + (size_t)19 * 1024 * 1024;

    convert_bf16<<<1024, 256, 0, stream>>>(x, wq, wk, wv, wo, xb, wqb, wkb, wvb, wob);
    qkv_bf16<<<dim3(32, 8, 3), 256, 0, stream>>>(xb, wqb, wkb, wvb, qf, kf, vf);
    retention_paired<<<1024, 256, 0, stream>>>(qf, kf, vf, gammas, ret);
    out_bf16<<<dim3(32, 8), 256, 0, stream>>>(ret, wob, out);
}